// Round 1
// baseline (298.272 us; speedup 1.0000x reference)
//
#include <hip/hip_runtime.h>

#define D 32
#define STEPSZ 1.0f

// ---------------------------------------------------------------------------
// K1: per-node precompute.  a[n] = x[n] . sheafW[0:D], b[n] = x[n] . sheafW[D:2D]
//     y[n,:] = lin_W @ x[n] + lin_b   (lin_W is [D,D] row-major, y_j = sum_d x_d * W[j,d])
// ---------------------------------------------------------------------------
__global__ void k_node_pre(const float* __restrict__ x,
                           const float* __restrict__ sheafW,
                           const float* __restrict__ linW,
                           const float* __restrict__ linb,
                           float* __restrict__ a, float* __restrict__ b,
                           float* __restrict__ y, int N) {
    __shared__ float sW[D * D];
    __shared__ float sB[D];
    __shared__ float sS[2 * D];
    for (int i = threadIdx.x; i < D * D; i += blockDim.x) sW[i] = linW[i];
    if (threadIdx.x < D) sB[threadIdx.x] = linb[threadIdx.x];
    if (threadIdx.x < 2 * D) sS[threadIdx.x] = sheafW[threadIdx.x];
    __syncthreads();

    int n = blockIdx.x * blockDim.x + threadIdx.x;
    if (n >= N) return;

    float xv[D];
    const float4* xp = reinterpret_cast<const float4*>(x + (size_t)n * D);
#pragma unroll
    for (int i = 0; i < D / 4; ++i) {
        float4 v = xp[i];
        xv[4 * i + 0] = v.x; xv[4 * i + 1] = v.y;
        xv[4 * i + 2] = v.z; xv[4 * i + 3] = v.w;
    }

    float av = 0.f, bv = 0.f;
#pragma unroll
    for (int d = 0; d < D; ++d) { av += xv[d] * sS[d]; bv += xv[d] * sS[D + d]; }
    a[n] = av;
    b[n] = bv;

    float4* yp = reinterpret_cast<float4*>(y + (size_t)n * D);
#pragma unroll
    for (int j4 = 0; j4 < D / 4; ++j4) {
        float4 o;
#pragma unroll
        for (int jj = 0; jj < 4; ++jj) {
            int j = 4 * j4 + jj;
            float s = sB[j];
#pragma unroll
            for (int d = 0; d < D; ++d) s += xv[d] * sW[j * D + d];
            (&o.x)[jj] = s;
        }
        yp[j4] = o;
    }
}

// ---------------------------------------------------------------------------
// K2: per-edge maps + diag segment-sum.
// ---------------------------------------------------------------------------
__global__ void k_edge_maps(const int* __restrict__ ei,
                            const float* __restrict__ a,
                            const float* __restrict__ b,
                            float* __restrict__ maps,
                            float* __restrict__ diag_maps, int E) {
    int e = blockIdx.x * blockDim.x + threadIdx.x;
    if (e >= E) return;
    int row = ei[e];
    int col = ei[E + e];
    float m = tanhf(a[row] + b[col]);
    maps[e] = m;
    atomicAdd(&diag_maps[row], m * m);
}

// ---------------------------------------------------------------------------
// K3: per-node normalization scalars.
// ---------------------------------------------------------------------------
__global__ void k_node_dsi(const float* __restrict__ diag_maps,
                           float* __restrict__ d_si,
                           float* __restrict__ diag, int N) {
    int n = blockIdx.x * blockDim.x + threadIdx.x;
    if (n >= N) return;
    float dm = diag_maps[n];
    float dsi = rsqrtf(dm + 1.0f);
    d_si[n] = dsi;
    diag[n] = dm * dsi * dsi;
}

// ---------------------------------------------------------------------------
// K4: per-edge scatter of norm_maps * y[col] into out (accumulator, pre-zeroed).
//     Half-wave (32 lanes == D) per edge; lane d handles dim d.
// ---------------------------------------------------------------------------
__global__ void k_edge_scatter(const int* __restrict__ ei,
                               const int* __restrict__ ridx,
                               const float* __restrict__ maps,
                               const float* __restrict__ d_si,
                               const float* __restrict__ y,
                               float* __restrict__ out, int E) {
    int half = threadIdx.x >> 5;             // 8 edges per 256-thread block
    int lane = threadIdx.x & 31;
    int e = blockIdx.x * 8 + half;
    if (e >= E) return;
    int row = ei[e];
    int col = ei[E + e];
    float m = maps[e];
    float mr = maps[ridx[e]];
    float nm = -(m * mr) * d_si[row] * d_si[col];
    float v = nm * y[(size_t)col * D + lane];
    atomicAdd(&out[(size_t)row * D + lane], v);
}

// ---------------------------------------------------------------------------
// K5: finalize out = x - STEP * (diag[n] * y + accum)
// ---------------------------------------------------------------------------
__global__ void k_finalize(const float* __restrict__ x,
                           const float* __restrict__ y,
                           const float* __restrict__ diag,
                           float* __restrict__ out, int ND) {
    int i = blockIdx.x * blockDim.x + threadIdx.x;
    if (i >= ND) return;
    int n = i >> 5;  // D == 32
    out[i] = x[i] - STEPSZ * (diag[n] * y[i] + out[i]);
}

extern "C" void kernel_launch(void* const* d_in, const int* in_sizes, int n_in,
                              void* d_out, int out_size, void* d_ws, size_t ws_size,
                              hipStream_t stream) {
    const float* x      = (const float*)d_in[0];
    const float* sheafW = (const float*)d_in[1];
    const float* linW   = (const float*)d_in[2];
    const float* linb   = (const float*)d_in[3];
    const int*   ei     = (const int*)d_in[4];
    const int*   ridx   = (const int*)d_in[5];

    int N = in_sizes[0] / D;
    int E = in_sizes[4] / 2;

    // Workspace layout (floats): a[N] b[N] y[N*D] diag_maps[N] d_si[N] diag[N] maps[E]
    float* ws        = (float*)d_ws;
    float* a         = ws;
    float* b         = a + N;
    float* y         = b + N;
    float* diag_maps = y + (size_t)N * D;
    float* d_si      = diag_maps + N;
    float* diag      = d_si + N;
    float* maps      = diag + N;

    float* out = (float*)d_out;

    hipMemsetAsync(diag_maps, 0, (size_t)N * sizeof(float), stream);
    hipMemsetAsync(out, 0, (size_t)out_size * sizeof(float), stream);

    const int B = 256;
    k_node_pre<<<(N + B - 1) / B, B, 0, stream>>>(x, sheafW, linW, linb, a, b, y, N);
    k_edge_maps<<<(E + B - 1) / B, B, 0, stream>>>(ei, a, b, maps, diag_maps, E);
    k_node_dsi<<<(N + B - 1) / B, B, 0, stream>>>(diag_maps, d_si, diag, N);
    k_edge_scatter<<<(E + 7) / 8, 256, 0, stream>>>(ei, ridx, maps, d_si, y, out, E);
    k_finalize<<<((size_t)N * D + B - 1) / B, B, 0, stream>>>(x, y, diag, out, N * D);
}